// Round 4
// baseline (54.218 us; speedup 1.0000x reference)
//
#include <hip/hip_runtime.h>
#include <hip/hip_bf16.h>

#define B_    4
#define C_    256
#define H_    180
#define W_    180
#define NBOX  64
#define HW_   (H_ * W_)
#define NPIX  (B_ * HW_)

// One thread per pixel (b,h,w). Computes box mask from gt_boxes in registers,
// then (only if masked) loops 256 channels with coalesced loads of input and
// target, accumulating 0.5*(x-t)^2 and any(t!=0). Block-reduces into a global
// float sum + int positive-count via one atomic per block.
__global__ __launch_bounds__(256) void mask_feat_loss_main(
    const float* __restrict__ x,
    const float* __restrict__ t,
    const int*   __restrict__ boxes,
    float*        ws_sum,
    unsigned int* ws_cnt)
{
    const int p = blockIdx.x * blockDim.x + threadIdx.x;

    float s = 0.0f;
    int   cnt = 0;

    if (p < NPIX) {
        const int b  = p / HW_;
        const int hw = p - b * HW_;
        const int h  = hw / W_;
        const int w  = hw - h * W_;

        // Box mask: inside = (h>=lt_y) & (h<rb_y) & (w>=rb_x) & (w<lt_x)
        bool mask = false;
        const int* bb = boxes + b * NBOX * 4;
        #pragma unroll 8
        for (int n = 0; n < NBOX; ++n) {
            const int ltx = bb[n * 4 + 0];
            const int lty = bb[n * 4 + 1];
            const int rbx = bb[n * 4 + 2];
            const int rby = bb[n * 4 + 3];
            mask |= ((h >= lty) & (h < rby) & (w >= rbx) & (w < ltx));
        }

        if (mask) {
            const float* xp = x + (size_t)b * C_ * HW_ + hw;
            const float* tp = t + (size_t)b * C_ * HW_ + hw;
            bool anynz = false;
            #pragma unroll 8
            for (int c = 0; c < C_; ++c) {
                const float tv = tp[(size_t)c * HW_];
                const float xv = xp[(size_t)c * HW_];
                anynz |= (tv != 0.0f);            // NaN != 0 is true (matches ref)
                const float d = xv - tv;
                float term = 0.5f * d * d;
                if (isnan(tv)) term = 0.0f;        // t = where(isnan(t), x, t)
                s += term;
            }
            if (anynz) cnt = 1;
            else       s = 0.0f;                   // all-zero target row: weight 0
        }
    }

    // Wave (64-lane) reduction
    #pragma unroll
    for (int off = 32; off > 0; off >>= 1) {
        s   += __shfl_down(s, off, 64);
        cnt += __shfl_down(cnt, off, 64);
    }

    __shared__ float ssum[4];
    __shared__ int   scnt[4];
    const int lane = threadIdx.x & 63;
    const int wid  = threadIdx.x >> 6;
    if (lane == 0) { ssum[wid] = s; scnt[wid] = cnt; }
    __syncthreads();

    if (threadIdx.x == 0) {
        const float S  = ssum[0] + ssum[1] + ssum[2] + ssum[3];
        const int   Cn = scnt[0] + scnt[1] + scnt[2] + scnt[3];
        if (S != 0.0f) atomicAdd(ws_sum, S);
        if (Cn != 0)   atomicAdd(ws_cnt, (unsigned int)Cn);
    }
}

__global__ void mask_feat_loss_finalize(const float* ws_sum,
                                        const unsigned int* ws_cnt,
                                        float* out)
{
    const float S = ws_sum[0];
    const float n = (float)ws_cnt[0];
    // loss = S / (C * pos_norm) summed, then / B
    out[0] = S / (n * (float)C_ * (float)B_);
}

extern "C" void kernel_launch(void* const* d_in, const int* in_sizes, int n_in,
                              void* d_out, int out_size, void* d_ws, size_t ws_size,
                              hipStream_t stream)
{
    const float* x     = (const float*)d_in[0];
    const float* t     = (const float*)d_in[1];
    const int*   boxes = (const int*)d_in[2];
    float* out = (float*)d_out;

    float*        ws_sum = (float*)d_ws;
    unsigned int* ws_cnt = (unsigned int*)((char*)d_ws + sizeof(float));

    // Zero the accumulators (ws is poisoned 0xAA and never re-poisoned).
    hipMemsetAsync(d_ws, 0, 2 * sizeof(unsigned int), stream);

    const int threads = 256;
    const int blocks  = (NPIX + threads - 1) / threads;
    mask_feat_loss_main<<<blocks, threads, 0, stream>>>(x, t, boxes, ws_sum, ws_cnt);
    mask_feat_loss_finalize<<<1, 1, 0, stream>>>(ws_sum, ws_cnt, out);
}